// Round 4
// baseline (212.754 us; speedup 1.0000x reference)
//
#include <hip/hip_runtime.h>
#include <math.h>

#define LOOKBACK 336
#define NFEAT    164
#define HORIZON  96
#define DMODEL   64
#define DSTATE   16
#define DINNER   128
#define MLPH     64
#define BATCH    512
#define XCP      132
#define NG       4      // channel-groups (time segments) per block
#define GSEG     84     // timesteps per group
#define CHK      12     // timesteps per chunk
#define NCH      7      // chunks per group (7*12 = 84)

typedef float v2f __attribute__((ext_vector_type(2)));

__device__ __forceinline__ float fast_rcp(float x) { return __builtin_amdgcn_rcpf(x); }
__device__ __forceinline__ float silu_f(float x) {
    return x * fast_rcp(1.f + __expf(-x));
}

// R0 structure (4 segments in one 512-thread block, no inter-block traffic),
// LDS 69->50KB: single xcbuf (scan reads xc from registers), h-partials via
// four contiguous float4[512] arrays union'd over the dead xcbuf.
// launch_bounds(512,2): second arg is min BLOCKS/CU (CUDA semantics) -- (512,6)
// in R3 crushed VGPRs to 40 and spilled xc_reg/H to scratch (75+103 MB HBM).
__global__ __launch_bounds__(512, 2) void mamba_one(
    const float* __restrict__ x_raw,   const float* __restrict__ x_features,
    const float* __restrict__ embed_W, const float* __restrict__ embed_b,
    const float* __restrict__ in_W,
    const float* __restrict__ conv_W,  const float* __restrict__ conv_b,
    const float* __restrict__ xproj_W, const float* __restrict__ dt_W,
    const float* __restrict__ dt_b,    const float* __restrict__ A_log,
    const float* __restrict__ Dvec,    const float* __restrict__ out_W,
    const float* __restrict__ mlp_W1,  const float* __restrict__ mlp_b1,
    const float* __restrict__ mlp_W2,  const float* __restrict__ mlp_b2,
    const float* __restrict__ head_W,  const float* __restrict__ head_b,
    float* __restrict__ out)
{
    __shared__ __align__(16) float xrl[344];            // xrl[i]=x_raw[i-3], pad i<3
    __shared__ __align__(16) float xprojT[20*XCP];      // 10.6 KB
    // union region: main loop = xcbuf[NG][CHK*XCP] (6336 floats);
    // after loop = hp[4][512] float4 partials (8192 floats = 32KB)
    __shared__ __align__(16) float xcu[8192];
    __shared__ __align__(16) float Bsh[NG][CHK][DSTATE];
    __shared__ __align__(16) float dtraw[NG][CHK][4];
    __shared__ float xcl[DINNER], zsil[DINNER], Cl[DSTATE], yv[DINNER];
    __shared__ float hfin[96], mlph[MLPH];

    const int tid = threadIdx.x;
    const int b   = blockIdx.x;
    const int g   = tid >> 7;            // group 0..3 (2 waves, wave-uniform)
    const int ch  = tid & 127;

    // ---- staging ----
    for (int i = tid; i < 339; i += 512)
        xrl[i] = (i >= 3) ? x_raw[b*LOOKBACK + i - 3] : 0.f;
    for (int idx = tid; idx < 20*DINNER; idx += 512) {
        int jj = idx >> 7, d = idx & 127;
        xprojT[jj*XCP + d] = xproj_W[d*36 + jj];
    }

    // ---- per-thread channel params (embed_* uniform -> scalar loads) ----
    float w1 = 0.f, w0 = 0.f;
    for (int dm = 0; dm < DMODEL; ++dm) {
        float w = in_W[dm*(2*DINNER) + ch];
        w1 = fmaf(embed_W[dm], w, w1);
        w0 = fmaf(embed_b[dm], w, w0);
    }
    const float4 cw = *(const float4*)&conv_W[ch*4];
    const float  cb = conv_b[ch];
    const float dtw0 = dt_W[ch],       dtw1 = dt_W[128 + ch],
                dtw2 = dt_W[256 + ch], dtw3 = dt_W[384 + ch];
    const float dtb_r = dt_b[ch];
    bool structured = true;
    #pragma unroll
    for (int i = 0; i < 16; ++i) {
        float a = __expf(A_log[ch*DSTATE + i]);
        float ex = (float)(i + 1);
        structured = structured && (fabsf(a - ex) < 1e-3f * ex);
    }
    const bool sfast = __all(structured);

    float xc_reg[CHK];                   // scan operand, register-carried
    float* const xcg = &xcu[g*(CHK*XCP)];
    __syncthreads();   // xrl/xprojT ready

    // ---- conv chunk 0 ----
    {
        const float* xr = &xrl[g*GSEG];
        if (g == 0) {        // zero-padded taps at sequence start
            #pragma unroll
            for (int tt = 0; tt < CHK; ++tt) {
                float acc = cb;
                if (tt >= 3) acc = fmaf(fmaf(xr[tt],   w1, w0), cw.x, acc);
                if (tt >= 2) acc = fmaf(fmaf(xr[tt+1], w1, w0), cw.y, acc);
                if (tt >= 1) acc = fmaf(fmaf(xr[tt+2], w1, w0), cw.z, acc);
                acc = fmaf(fmaf(xr[tt+3], w1, w0), cw.w, acc);
                float v = silu_f(acc);
                xcg[tt*XCP + ch] = v;
                xc_reg[tt] = v;
            }
        } else {
            float e0 = fmaf(xr[0], w1, w0);
            float e1 = fmaf(xr[1], w1, w0);
            float e2 = fmaf(xr[2], w1, w0);
            #pragma unroll
            for (int tt = 0; tt < CHK; ++tt) {
                float e3 = fmaf(xr[tt+3], w1, w0);
                float acc = cb + e0*cw.x + e1*cw.y + e2*cw.z + e3*cw.w;
                float v = silu_f(acc);
                xcg[tt*XCP + ch] = v;
                xc_reg[tt] = v;
                e0 = e1; e1 = e2; e2 = e3;
            }
        }
    }
    __syncthreads();

    // ---- main loop: A2(c) | bar | scan(c) + conv(c+1) | bar ----
    v2f h01={0,0},h23={0,0},h45={0,0},h67={0,0},
        h89={0,0},hAB={0,0},hCD={0,0},hEF={0,0};
    float dacc = 0.f;

    for (int c = 0; c < NCH; ++c) {
        // A2: [12 x 128] @ [128 x 20] -> dtraw(4)+Bsh(16); 120 tasks, 1t x 2j
        if (ch < 120) {
            const int tt = ch / 10;
            const int j0 = (ch - tt*10) * 2;
            const float* p0   = &xprojT[j0*XCP];
            const float* p1   = &xprojT[(j0+1)*XCP];
            const float* xrow = &xcg[tt*XCP];
            v2f a0 = {0,0}, a1 = {0,0};
            #pragma unroll 8
            for (int d = 0; d < DINNER; d += 4) {
                float4 xv = *(const float4*)(xrow + d);
                float4 q0 = *(const float4*)(p0 + d);
                float4 q1 = *(const float4*)(p1 + d);
                v2f xl = {xv.x, xv.y}, xh = {xv.z, xv.w};
                v2f q0l = {q0.x, q0.y}, q0h = {q0.z, q0.w};
                v2f q1l = {q1.x, q1.y}, q1h = {q1.z, q1.w};
                a0 = __builtin_elementwise_fma(xl, q0l, a0);
                a0 = __builtin_elementwise_fma(xh, q0h, a0);
                a1 = __builtin_elementwise_fma(xl, q1l, a1);
                a1 = __builtin_elementwise_fma(xh, q1h, a1);
            }
            float r0 = a0.x + a0.y, r1 = a1.x + a1.y;
            if (j0 < 4) *(float2*)&dtraw[g][tt][j0] = make_float2(r0, r1);
            else        *(float2*)&Bsh[g][tt][j0-4] = make_float2(r0, r1);
        }
        __syncthreads();   // A2 done: xcbuf free to overwrite, dtraw/Bsh ready

        // scan chunk c (xc in registers); conv chunk c+1 overwrites xcbuf
        // in the same phase (nothing reads xcbuf until after the barrier).
        if (__builtin_expect(sfast, 1)) {
            #pragma unroll
            for (int tt = 0; tt < CHK; ++tt) {
                float4 dr = *(const float4*)&dtraw[g][tt][0];    // broadcast
                float dv = fmaf(dr.x, dtw0, fmaf(dr.y, dtw1,
                           fmaf(dr.z, dtw2, fmaf(dr.w, dtw3, dtb_r))));
                float e  = __expf(dv);
                float p  = 1.f + e;
                float r  = fast_rcp(p);                  // exp(-delta)
                float dl = (dv > 80.f) ? dv : __logf(p); // delta
                dacc += dl;
                float ux = dl * xc_reg[tt];
                float4 B0 = *(const float4*)&Bsh[g][tt][0];
                float4 B1 = *(const float4*)&Bsh[g][tt][4];
                float4 B2 = *(const float4*)&Bsh[g][tt][8];
                float4 B3 = *(const float4*)&Bsh[g][tt][12];
                float r2 = r*r;
                v2f r2v = {r2, r2};
                v2f p01 = {r, r2};
                v2f p23 = p01*r2v, p45 = p23*r2v, p67 = p45*r2v, p89 = p67*r2v,
                    pAB = p89*r2v, pCD = pAB*r2v, pEF = pCD*r2v;
                v2f uxv = {ux, ux};
                h01 = __builtin_elementwise_fma(p01, h01, uxv*(v2f){B0.x,B0.y});
                h23 = __builtin_elementwise_fma(p23, h23, uxv*(v2f){B0.z,B0.w});
                h45 = __builtin_elementwise_fma(p45, h45, uxv*(v2f){B1.x,B1.y});
                h67 = __builtin_elementwise_fma(p67, h67, uxv*(v2f){B1.z,B1.w});
                h89 = __builtin_elementwise_fma(p89, h89, uxv*(v2f){B2.x,B2.y});
                hAB = __builtin_elementwise_fma(pAB, hAB, uxv*(v2f){B2.z,B2.w});
                hCD = __builtin_elementwise_fma(pCD, hCD, uxv*(v2f){B3.x,B3.y});
                hEF = __builtin_elementwise_fma(pEF, hEF, uxv*(v2f){B3.z,B3.w});
            }
        } else {
            const float* Arow = A_log + ch*DSTATE;
            #pragma unroll
            for (int tt = 0; tt < CHK; ++tt) {
                float4 dr = *(const float4*)&dtraw[g][tt][0];
                float dv = fmaf(dr.x, dtw0, fmaf(dr.y, dtw1,
                           fmaf(dr.z, dtw2, fmaf(dr.w, dtw3, dtb_r))));
                float e  = __expf(dv);
                float dl = (dv > 15.f) ? dv : __logf(1.f + e);
                dacc += dl;
                float ux = dl * xc_reg[tt];
                const float* Brow = &Bsh[g][tt][0];
                float hv[16] = {h01.x,h01.y,h23.x,h23.y,h45.x,h45.y,h67.x,h67.y,
                                h89.x,h89.y,hAB.x,hAB.y,hCD.x,hCD.y,hEF.x,hEF.y};
                for (int i = 0; i < 16; ++i)
                    hv[i] = fmaf(__expf(-__expf(Arow[i])*dl), hv[i], ux*Brow[i]);
                h01=(v2f){hv[0],hv[1]};   h23=(v2f){hv[2],hv[3]};
                h45=(v2f){hv[4],hv[5]};   h67=(v2f){hv[6],hv[7]};
                h89=(v2f){hv[8],hv[9]};   hAB=(v2f){hv[10],hv[11]};
                hCD=(v2f){hv[12],hv[13]}; hEF=(v2f){hv[14],hv[15]};
            }
        }

        if (c + 1 < NCH) {   // conv chunk c+1 into the (now free) buffer
            const float* xr = &xrl[g*GSEG + (c+1)*CHK];
            float e0 = fmaf(xr[0], w1, w0);
            float e1 = fmaf(xr[1], w1, w0);
            float e2 = fmaf(xr[2], w1, w0);
            float v = 0.f;
            #pragma unroll
            for (int tt = 0; tt < CHK; ++tt) {
                float e3 = fmaf(xr[tt+3], w1, w0);
                float acc = cb + e0*cw.x + e1*cw.y + e2*cw.z + e3*cw.w;
                v = silu_f(acc);
                xcg[tt*XCP + ch] = v;
                xc_reg[tt] = v;
                e0 = e1; e1 = e2; e2 = e3;
            }
            if (g == NG-1 && c + 1 == NCH-1) xcl[ch] = v;    // t = 335
        }
        __syncthreads();   // conv writes done before next A2; scan done
    }

    // ---- write partials: hp[q][512] float4 arrays over dead xcbuf ----
    float4* const hp4 = (float4*)xcu;    // hp4[q*512 + idx]
    float*  const dsum = &Bsh[0][0][0];  // needs 512 <= 768
    {
        const int idx = g*128 + ch;
        hp4[0*512 + idx] = make_float4(h01.x,h01.y,h23.x,h23.y);
        hp4[1*512 + idx] = make_float4(h45.x,h45.y,h67.x,h67.y);
        hp4[2*512 + idx] = make_float4(h89.x,h89.y,hAB.x,hAB.y);
        hp4[3*512 + idx] = make_float4(hCD.x,hCD.y,hEF.x,hEF.y);
        dsum[idx] = dacc;
    }
    __syncthreads();

    // ---- E1 (parallel): combine | z-gate | C | mlp1 ----
    float H[16];
    if (tid < 128) {
        {
            float4 a  = hp4[0*512 + tid], bq = hp4[1*512 + tid];
            float4 cq = hp4[2*512 + tid], dq = hp4[3*512 + tid];
            H[0]=a.x;  H[1]=a.y;  H[2]=a.z;  H[3]=a.w;
            H[4]=bq.x; H[5]=bq.y; H[6]=bq.z; H[7]=bq.w;
            H[8]=cq.x; H[9]=cq.y; H[10]=cq.z;H[11]=cq.w;
            H[12]=dq.x;H[13]=dq.y;H[14]=dq.z;H[15]=dq.w;
        }
        for (int gg = 1; gg < NG; ++gg) {
            float D = dsum[gg*128 + tid];
            float4 a  = hp4[0*512 + gg*128 + tid], bq = hp4[1*512 + gg*128 + tid];
            float4 cq = hp4[2*512 + gg*128 + tid], dq = hp4[3*512 + gg*128 + tid];
            float hg[16] = {a.x,a.y,a.z,a.w,bq.x,bq.y,bq.z,bq.w,
                            cq.x,cq.y,cq.z,cq.w,dq.x,dq.y,dq.z,dq.w};
            if (structured) {
                float r = __expf(-D);
                float pw = 1.f;
                #pragma unroll
                for (int i = 0; i < 16; ++i) {
                    pw *= r;                      // r^(i+1)
                    H[i] = fmaf(pw, H[i], hg[i]);
                }
            } else {
                #pragma unroll
                for (int i = 0; i < 16; ++i)
                    H[i] = fmaf(__expf(-__expf(A_log[tid*DSTATE+i])*D), H[i], hg[i]);
            }
        }
    } else if (tid < 256) {
        const int c2 = tid - 128;                 // z-gate channel
        float a1 = 0.f, a0 = 0.f;
        for (int dm = 0; dm < DMODEL; ++dm) {
            float w = in_W[dm*(2*DINNER) + DINNER + c2];
            a1 = fmaf(embed_W[dm], w, a1);
            a0 = fmaf(embed_b[dm], w, a0);
        }
        float zv = fmaf(xrl[338], a1, a0);        // x_raw[335]
        zsil[c2] = silu_f(zv);
    } else if (tid < 320) {
        const int lane = tid - 256;               // C at t=335 (one wave)
        const int n = lane & 15, q = lane >> 4;
        float acc = 0.f;
        for (int d = q*32; d < q*32 + 32; ++d)
            acc = fmaf(xcl[d], xproj_W[d*36 + 20 + n], acc);
        acc += __shfl_xor(acc, 16);
        acc += __shfl_xor(acc, 32);
        if (lane < 16) Cl[n] = acc;
    } else if (tid >= 384) {
        const int lane = tid - 384;               // mlp1 (2 waves)
        const int j = lane >> 1, k = lane & 1;
        const float* xf = x_features + b*NFEAT;
        float acc = 0.f;
        const int f0 = k*82, f1 = (k ? NFEAT : 82);
        for (int f = f0; f < f1; ++f)
            acc = fmaf(xf[f], mlp_W1[f*MLPH + j], acc);
        acc += __shfl_xor(acc, 1);
        if (k == 0) mlph[j] = fmaxf(acc + mlp_b1[j], 0.f);
    }
    __syncthreads();

    // ---- E2: y (tid<128) | mlp2 (tid 128..191) ----
    if (tid < 128) {
        float acc = 0.f;
        #pragma unroll
        for (int i = 0; i < 16; ++i) acc = fmaf(H[i], Cl[i], acc);
        float y = acc + xcl[tid]*Dvec[tid];
        yv[tid] = y * zsil[tid];
    } else if (tid < 192) {
        const int lane = tid - 128;
        const int j = lane >> 1, k = lane & 1;
        float acc = 0.f;
        for (int kk = k*32; kk < k*32 + 32; ++kk)
            acc = fmaf(mlph[kk], mlp_W2[kk*32 + j], acc);
        acc += __shfl_xor(acc, 1);
        if (k == 0) hfin[64 + j] = acc + mlp_b2[j];
    }
    __syncthreads();

    // ---- E3: out projection (tid<256) ----
    if (tid < 256) {
        const int o = tid >> 2, k = tid & 3;
        float acc = 0.f;
        for (int d = k*32; d < k*32 + 32; ++d)
            acc = fmaf(yv[d], out_W[d*DMODEL + o], acc);
        acc += __shfl_xor(acc, 1);
        acc += __shfl_xor(acc, 2);
        if (k == 0) hfin[o] = acc;
    }
    __syncthreads();

    // ---- E4: head ----
    if (tid < 192) {
        const int o = tid >> 1, k = tid & 1;
        float acc = 0.f;
        for (int i = k*48; i < k*48 + 48; ++i)
            acc = fmaf(hfin[i], head_W[i*HORIZON + o], acc);
        acc += __shfl_xor(acc, 1);
        if (k == 0) out[b*HORIZON + o] = acc + head_b[o];
    }
}

extern "C" void kernel_launch(void* const* d_in, const int* in_sizes, int n_in,
                              void* d_out, int out_size, void* d_ws, size_t ws_size,
                              hipStream_t stream) {
    (void)in_sizes; (void)n_in; (void)out_size; (void)d_ws; (void)ws_size;
    mamba_one<<<BATCH, 512, 0, stream>>>(
        (const float*)d_in[0],  (const float*)d_in[1],  (const float*)d_in[2],
        (const float*)d_in[3],  (const float*)d_in[4],  (const float*)d_in[5],
        (const float*)d_in[6],  (const float*)d_in[7],  (const float*)d_in[8],
        (const float*)d_in[9],  (const float*)d_in[10], (const float*)d_in[11],
        (const float*)d_in[12], (const float*)d_in[13], (const float*)d_in[14],
        (const float*)d_in[15], (const float*)d_in[16], (const float*)d_in[17],
        (const float*)d_in[18], (float*)d_out);
}

// Round 5
// 169.430 us; speedup vs baseline: 1.2557x; 1.2557x over previous
//
#include <hip/hip_runtime.h>
#include <math.h>

#define LOOKBACK 336
#define NFEAT    164
#define HORIZON  96
#define DMODEL   64
#define DSTATE   16
#define DINNER   128
#define MLPH     64
#define BATCH    512
#define XCP      132
#define NG       4      // channel-groups (time segments) per block
#define GSEG     84     // timesteps per group
#define CHK      12     // timesteps per chunk
#define NCH      7      // chunks per group (7*12 = 84)
#define HSTR     20     // hpart record stride (breaks stride-16 bank aliasing)

typedef float v2f __attribute__((ext_vector_type(2)));

__device__ __forceinline__ float fast_rcp(float x) { return __builtin_amdgcn_rcpf(x); }
__device__ __forceinline__ float silu_f(float x) {
    return x * fast_rcp(1.f + __expf(-x));
}

// R0 baseline (99us on-device) with ONE change: A2 task map is jpair-major
// (jp=ch/12, tt=ch%12) instead of tt-major. Within a wave instruction, lanes
// now share the same xproj column (broadcast) with only 2-way alias across
// jp (free), and xrow reads are 2-way max -- both A2 read streams
// bank-conflict-free. tt-major had ~3-way conflicts on the 64 xproj
// ds_read_b128 per lane per chunk. VGPR-neutral (stay <=64: R4 showed the
// 64-VGPR occupancy cliff costs ~40%).
__global__ __launch_bounds__(512, 2) void mamba_one(
    const float* __restrict__ x_raw,   const float* __restrict__ x_features,
    const float* __restrict__ embed_W, const float* __restrict__ embed_b,
    const float* __restrict__ in_W,
    const float* __restrict__ conv_W,  const float* __restrict__ conv_b,
    const float* __restrict__ xproj_W, const float* __restrict__ dt_W,
    const float* __restrict__ dt_b,    const float* __restrict__ A_log,
    const float* __restrict__ Dvec,    const float* __restrict__ out_W,
    const float* __restrict__ mlp_W1,  const float* __restrict__ mlp_b1,
    const float* __restrict__ mlp_W2,  const float* __restrict__ mlp_b2,
    const float* __restrict__ head_W,  const float* __restrict__ head_b,
    float* __restrict__ out)
{
    __shared__ __align__(16) float xrl[344];            // xrl[i]=x_raw[i-3], pad i<3
    __shared__ __align__(16) float xprojT[20*XCP];      // 10.6 KB
    __shared__ __align__(16) float xcbuf[2][NG][CHK*XCP]; // 50.7 KB double-buffered
    __shared__ __align__(16) float Bsh[NG][CHK][DSTATE];
    __shared__ __align__(16) float dtraw[NG][CHK][4];
    __shared__ float xcl[DINNER], zsil[DINNER], Cl[DSTATE], yv[DINNER];
    __shared__ float hfin[96], mlph[MLPH];

    const int tid = threadIdx.x;
    const int b   = blockIdx.x;
    const int g   = tid >> 7;            // group 0..3 (2 waves, wave-uniform)
    const int ch  = tid & 127;

    // ---- staging ----
    for (int i = tid; i < 339; i += 512)
        xrl[i] = (i >= 3) ? x_raw[b*LOOKBACK + i - 3] : 0.f;
    for (int idx = tid; idx < 20*DINNER; idx += 512) {
        int jj = idx >> 7, d = idx & 127;
        xprojT[jj*XCP + d] = xproj_W[d*36 + jj];
    }

    // ---- per-thread channel params (embed_* uniform -> scalar loads) ----
    float w1 = 0.f, w0 = 0.f;
    for (int dm = 0; dm < DMODEL; ++dm) {
        float w = in_W[dm*(2*DINNER) + ch];
        w1 = fmaf(embed_W[dm], w, w1);
        w0 = fmaf(embed_b[dm], w, w0);
    }
    const float4 cw = *(const float4*)&conv_W[ch*4];
    const float  cb = conv_b[ch];
    const float dtw0 = dt_W[ch],       dtw1 = dt_W[128 + ch],
                dtw2 = dt_W[256 + ch], dtw3 = dt_W[384 + ch];
    const float dtb_r = dt_b[ch];
    bool structured = true;
    #pragma unroll
    for (int i = 0; i < 16; ++i) {
        float a = __expf(A_log[ch*DSTATE + i]);
        float ex = (float)(i + 1);
        structured = structured && (fabsf(a - ex) < 1e-3f * ex);
    }
    const bool sfast = __all(structured);
    __syncthreads();   // xrl/xprojT ready

    // ---- conv chunk 0 into buffer 0 ----
    {
        float* xw = &xcbuf[0][g][0];
        const float* xr = &xrl[g*GSEG];
        if (g == 0) {        // zero-padded taps at sequence start
            for (int tt = 0; tt < CHK; ++tt) {
                float acc = cb;
                if (tt >= 3) acc = fmaf(fmaf(xr[tt],   w1, w0), cw.x, acc);
                if (tt >= 2) acc = fmaf(fmaf(xr[tt+1], w1, w0), cw.y, acc);
                if (tt >= 1) acc = fmaf(fmaf(xr[tt+2], w1, w0), cw.z, acc);
                acc = fmaf(fmaf(xr[tt+3], w1, w0), cw.w, acc);
                xw[tt*XCP + ch] = silu_f(acc);
            }
        } else {
            float e0 = fmaf(xr[0], w1, w0);
            float e1 = fmaf(xr[1], w1, w0);
            float e2 = fmaf(xr[2], w1, w0);
            #pragma unroll
            for (int tt = 0; tt < CHK; ++tt) {
                float e3 = fmaf(xr[tt+3], w1, w0);
                float acc = cb + e0*cw.x + e1*cw.y + e2*cw.z + e3*cw.w;
                xw[tt*XCP + ch] = silu_f(acc);
                e0 = e1; e1 = e2; e2 = e3;
            }
        }
    }
    __syncthreads();

    // ---- main loop: A2(c) | bar | scan(c) || conv(c+1) | bar ----
    v2f h01={0,0},h23={0,0},h45={0,0},h67={0,0},
        h89={0,0},hAB={0,0},hCD={0,0},hEF={0,0};
    float dacc = 0.f;

    for (int c = 0; c < NCH; ++c) {
        const int buf = c & 1;

        // A2: [12 x 128] @ [128 x 20] -> dtraw(4)+Bsh(16); 120 tasks,
        // jpair-major: lanes 12k..12k+11 share xproj columns (broadcast).
        if (ch < 120) {
            const int jp = ch / 12;          // 0..9
            const int tt = ch - jp*12;       // 0..11
            const int j0 = jp*2;
            const float* p0   = &xprojT[j0*XCP];
            const float* p1   = &xprojT[(j0+1)*XCP];
            const float* xrow = &xcbuf[buf][g][tt*XCP];
            v2f a0 = {0,0}, a1 = {0,0};
            #pragma unroll 8
            for (int d = 0; d < DINNER; d += 4) {
                float4 xv = *(const float4*)(xrow + d);
                float4 q0 = *(const float4*)(p0 + d);
                float4 q1 = *(const float4*)(p1 + d);
                v2f xl = {xv.x, xv.y}, xh = {xv.z, xv.w};
                v2f q0l = {q0.x, q0.y}, q0h = {q0.z, q0.w};
                v2f q1l = {q1.x, q1.y}, q1h = {q1.z, q1.w};
                a0 = __builtin_elementwise_fma(xl, q0l, a0);
                a0 = __builtin_elementwise_fma(xh, q0h, a0);
                a1 = __builtin_elementwise_fma(xl, q1l, a1);
                a1 = __builtin_elementwise_fma(xh, q1h, a1);
            }
            float r0 = a0.x + a0.y, r1 = a1.x + a1.y;
            if (j0 < 4) *(float2*)&dtraw[g][tt][j0] = make_float2(r0, r1);
            else        *(float2*)&Bsh[g][tt][j0-4] = make_float2(r0, r1);
        }
        __syncthreads();

        // scan chunk c (reads buf) — conv chunk c+1 (writes buf^1) follows in
        // the SAME phase: independent stream fills the scan's trans latency.
        const float* xs = &xcbuf[buf][g][0];
        if (__builtin_expect(sfast, 1)) {
            #pragma unroll
            for (int tt = 0; tt < CHK; ++tt) {
                float4 dr = *(const float4*)&dtraw[g][tt][0];    // broadcast
                float dv = fmaf(dr.x, dtw0, fmaf(dr.y, dtw1,
                           fmaf(dr.z, dtw2, fmaf(dr.w, dtw3, dtb_r))));
                float e  = __expf(dv);
                float p  = 1.f + e;
                float r  = fast_rcp(p);                  // exp(-delta)
                float dl = (dv > 80.f) ? dv : __logf(p); // delta
                dacc += dl;
                float ux = dl * xs[tt*XCP + ch];
                float4 B0 = *(const float4*)&Bsh[g][tt][0];
                float4 B1 = *(const float4*)&Bsh[g][tt][4];
                float4 B2 = *(const float4*)&Bsh[g][tt][8];
                float4 B3 = *(const float4*)&Bsh[g][tt][12];
                float r2 = r*r;
                v2f r2v = {r2, r2};
                v2f p01 = {r, r2};
                v2f p23 = p01*r2v, p45 = p23*r2v, p67 = p45*r2v, p89 = p67*r2v,
                    pAB = p89*r2v, pCD = pAB*r2v, pEF = pCD*r2v;
                v2f uxv = {ux, ux};
                h01 = __builtin_elementwise_fma(p01, h01, uxv*(v2f){B0.x,B0.y});
                h23 = __builtin_elementwise_fma(p23, h23, uxv*(v2f){B0.z,B0.w});
                h45 = __builtin_elementwise_fma(p45, h45, uxv*(v2f){B1.x,B1.y});
                h67 = __builtin_elementwise_fma(p67, h67, uxv*(v2f){B1.z,B1.w});
                h89 = __builtin_elementwise_fma(p89, h89, uxv*(v2f){B2.x,B2.y});
                hAB = __builtin_elementwise_fma(pAB, hAB, uxv*(v2f){B2.z,B2.w});
                hCD = __builtin_elementwise_fma(pCD, hCD, uxv*(v2f){B3.x,B3.y});
                hEF = __builtin_elementwise_fma(pEF, hEF, uxv*(v2f){B3.z,B3.w});
            }
        } else {
            const float* Arow = A_log + ch*DSTATE;
            for (int tt = 0; tt < CHK; ++tt) {
                float4 dr = *(const float4*)&dtraw[g][tt][0];
                float dv = fmaf(dr.x, dtw0, fmaf(dr.y, dtw1,
                           fmaf(dr.z, dtw2, fmaf(dr.w, dtw3, dtb_r))));
                float e  = __expf(dv);
                float dl = (dv > 15.f) ? dv : __logf(1.f + e);
                dacc += dl;
                float ux = dl * xs[tt*XCP + ch];
                const float* Brow = &Bsh[g][tt][0];
                float hv[16] = {h01.x,h01.y,h23.x,h23.y,h45.x,h45.y,h67.x,h67.y,
                                h89.x,h89.y,hAB.x,hAB.y,hCD.x,hCD.y,hEF.x,hEF.y};
                for (int i = 0; i < 16; ++i)
                    hv[i] = fmaf(__expf(-__expf(Arow[i])*dl), hv[i], ux*Brow[i]);
                h01=(v2f){hv[0],hv[1]};   h23=(v2f){hv[2],hv[3]};
                h45=(v2f){hv[4],hv[5]};   h67=(v2f){hv[6],hv[7]};
                h89=(v2f){hv[8],hv[9]};   hAB=(v2f){hv[10],hv[11]};
                hCD=(v2f){hv[12],hv[13]}; hEF=(v2f){hv[14],hv[15]};
            }
        }

        if (c + 1 < NCH) {   // conv chunk c+1 into the other buffer (t0 >= 12)
            float* xw = &xcbuf[buf^1][g][0];
            const float* xr = &xrl[g*GSEG + (c+1)*CHK];
            float e0 = fmaf(xr[0], w1, w0);
            float e1 = fmaf(xr[1], w1, w0);
            float e2 = fmaf(xr[2], w1, w0);
            float v = 0.f;
            #pragma unroll
            for (int tt = 0; tt < CHK; ++tt) {
                float e3 = fmaf(xr[tt+3], w1, w0);
                float acc = cb + e0*cw.x + e1*cw.y + e2*cw.z + e3*cw.w;
                v = silu_f(acc);
                xw[tt*XCP + ch] = v;
                e0 = e1; e1 = e2; e2 = e3;
            }
            if (g == NG-1 && c + 1 == NCH-1) xcl[ch] = v;    // t = 335
        }
        __syncthreads();   // scan reads + conv writes done before next A2
    }

    // ---- write partials to LDS (overlay dead xcbuf / Bsh regions) ----
    float* hpart = &xcbuf[0][0][0];      // needs 512*HSTR = 10240 <= 12672
    float* dsum  = &Bsh[0][0][0];        // needs 512 <= 768
    {
        float4* hp = (float4*)&hpart[(g*128 + ch)*HSTR];
        hp[0] = make_float4(h01.x,h01.y,h23.x,h23.y);
        hp[1] = make_float4(h45.x,h45.y,h67.x,h67.y);
        hp[2] = make_float4(h89.x,h89.y,hAB.x,hAB.y);
        hp[3] = make_float4(hCD.x,hCD.y,hEF.x,hEF.y);
        dsum[g*128 + ch] = dacc;
    }
    __syncthreads();

    // ---- E1 (parallel): combine | z-gate | C | mlp1 ----
    float H[16];
    if (tid < 128) {
        {
            const float4* hp = (const float4*)&hpart[tid*HSTR];
            float4 a = hp[0], bq = hp[1], cq = hp[2], dq = hp[3];
            H[0]=a.x;  H[1]=a.y;  H[2]=a.z;  H[3]=a.w;
            H[4]=bq.x; H[5]=bq.y; H[6]=bq.z; H[7]=bq.w;
            H[8]=cq.x; H[9]=cq.y; H[10]=cq.z;H[11]=cq.w;
            H[12]=dq.x;H[13]=dq.y;H[14]=dq.z;H[15]=dq.w;
        }
        for (int gg = 1; gg < NG; ++gg) {
            float D = dsum[gg*128 + tid];
            const float4* hp = (const float4*)&hpart[(gg*128 + tid)*HSTR];
            float4 a = hp[0], bq = hp[1], cq = hp[2], dq = hp[3];
            float hg[16] = {a.x,a.y,a.z,a.w,bq.x,bq.y,bq.z,bq.w,
                            cq.x,cq.y,cq.z,cq.w,dq.x,dq.y,dq.z,dq.w};
            if (structured) {
                float r = __expf(-D);
                float pw = 1.f;
                #pragma unroll
                for (int i = 0; i < 16; ++i) {
                    pw *= r;                      // r^(i+1)
                    H[i] = fmaf(pw, H[i], hg[i]);
                }
            } else {
                #pragma unroll
                for (int i = 0; i < 16; ++i)
                    H[i] = fmaf(__expf(-__expf(A_log[tid*DSTATE+i])*D), H[i], hg[i]);
            }
        }
    } else if (tid < 256) {
        const int c2 = tid - 128;                 // z-gate channel
        float a1 = 0.f, a0 = 0.f;
        for (int dm = 0; dm < DMODEL; ++dm) {
            float w = in_W[dm*(2*DINNER) + DINNER + c2];
            a1 = fmaf(embed_W[dm], w, a1);
            a0 = fmaf(embed_b[dm], w, a0);
        }
        float zv = fmaf(xrl[338], a1, a0);        // x_raw[335]
        zsil[c2] = silu_f(zv);
    } else if (tid < 320) {
        const int lane = tid - 256;               // C at t=335 (one wave)
        const int n = lane & 15, q = lane >> 4;
        float acc = 0.f;
        for (int d = q*32; d < q*32 + 32; ++d)
            acc = fmaf(xcl[d], xproj_W[d*36 + 20 + n], acc);
        acc += __shfl_xor(acc, 16);
        acc += __shfl_xor(acc, 32);
        if (lane < 16) Cl[n] = acc;
    } else if (tid >= 384) {
        const int lane = tid - 384;               // mlp1 (2 waves)
        const int j = lane >> 1, k = lane & 1;
        const float* xf = x_features + b*NFEAT;
        float acc = 0.f;
        const int f0 = k*82, f1 = (k ? NFEAT : 82);
        for (int f = f0; f < f1; ++f)
            acc = fmaf(xf[f], mlp_W1[f*MLPH + j], acc);
        acc += __shfl_xor(acc, 1);
        if (k == 0) mlph[j] = fmaxf(acc + mlp_b1[j], 0.f);
    }
    __syncthreads();

    // ---- E2: y (tid<128) | mlp2 (tid 128..191) ----
    if (tid < 128) {
        float acc = 0.f;
        #pragma unroll
        for (int i = 0; i < 16; ++i) acc = fmaf(H[i], Cl[i], acc);
        float y = acc + xcl[tid]*Dvec[tid];
        yv[tid] = y * zsil[tid];
    } else if (tid < 192) {
        const int lane = tid - 128;
        const int j = lane >> 1, k = lane & 1;
        float acc = 0.f;
        for (int kk = k*32; kk < k*32 + 32; ++kk)
            acc = fmaf(mlph[kk], mlp_W2[kk*32 + j], acc);
        acc += __shfl_xor(acc, 1);
        if (k == 0) hfin[64 + j] = acc + mlp_b2[j];
    }
    __syncthreads();

    // ---- E3: out projection (tid<256) ----
    if (tid < 256) {
        const int o = tid >> 2, k = tid & 3;
        float acc = 0.f;
        for (int d = k*32; d < k*32 + 32; ++d)
            acc = fmaf(yv[d], out_W[d*DMODEL + o], acc);
        acc += __shfl_xor(acc, 1);
        acc += __shfl_xor(acc, 2);
        if (k == 0) hfin[o] = acc;
    }
    __syncthreads();

    // ---- E4: head ----
    if (tid < 192) {
        const int o = tid >> 1, k = tid & 1;
        float acc = 0.f;
        for (int i = k*48; i < k*48 + 48; ++i)
            acc = fmaf(hfin[i], head_W[i*HORIZON + o], acc);
        acc += __shfl_xor(acc, 1);
        if (k == 0) out[b*HORIZON + o] = acc + head_b[o];
    }
}

extern "C" void kernel_launch(void* const* d_in, const int* in_sizes, int n_in,
                              void* d_out, int out_size, void* d_ws, size_t ws_size,
                              hipStream_t stream) {
    (void)in_sizes; (void)n_in; (void)out_size; (void)d_ws; (void)ws_size;
    mamba_one<<<BATCH, 512, 0, stream>>>(
        (const float*)d_in[0],  (const float*)d_in[1],  (const float*)d_in[2],
        (const float*)d_in[3],  (const float*)d_in[4],  (const float*)d_in[5],
        (const float*)d_in[6],  (const float*)d_in[7],  (const float*)d_in[8],
        (const float*)d_in[9],  (const float*)d_in[10], (const float*)d_in[11],
        (const float*)d_in[12], (const float*)d_in[13], (const float*)d_in[14],
        (const float*)d_in[15], (const float*)d_in[16], (const float*)d_in[17],
        (const float*)d_in[18], (float*)d_out);
}

// Round 6
// 167.488 us; speedup vs baseline: 1.2703x; 1.0116x over previous
//
#include <hip/hip_runtime.h>
#include <math.h>

#define LOOKBACK 336
#define NFEAT    164
#define HORIZON  96
#define DMODEL   64
#define DSTATE   16
#define DINNER   128
#define MLPH     64
#define BATCH    512
#define XCP      132
#define NG       4      // channel-groups (time segments) per block
#define GSEG     84     // timesteps per group
#define CHK      12     // timesteps per chunk
#define NCH      7      // chunks per group (7*12 = 84)
#define HSTR     20     // hpart record stride (breaks stride-16 bank aliasing)

typedef float v2f __attribute__((ext_vector_type(2)));

__device__ __forceinline__ float fast_rcp(float x) { return __builtin_amdgcn_rcpf(x); }
__device__ __forceinline__ float silu_f(float x) {
    return x * fast_rcp(1.f + __expf(-x));
}

// R5 (95us on-device) + pair-A2: the A2 projection is done by 240 lanes
// (waves 0-3), each covering one (jp,tt) task for TWO groups, so the
// chunk-invariant xproj column pair is read ONCE per two dot products.
// Block-wide A2 ds_read_b128 count drops 768 -> 512 per chunk (the LDS pipe
// is the measured bottleneck: ~16.8k cyc/block/chunk ~= kernel duration).
__global__ __launch_bounds__(512, 2) void mamba_one(
    const float* __restrict__ x_raw,   const float* __restrict__ x_features,
    const float* __restrict__ embed_W, const float* __restrict__ embed_b,
    const float* __restrict__ in_W,
    const float* __restrict__ conv_W,  const float* __restrict__ conv_b,
    const float* __restrict__ xproj_W, const float* __restrict__ dt_W,
    const float* __restrict__ dt_b,    const float* __restrict__ A_log,
    const float* __restrict__ Dvec,    const float* __restrict__ out_W,
    const float* __restrict__ mlp_W1,  const float* __restrict__ mlp_b1,
    const float* __restrict__ mlp_W2,  const float* __restrict__ mlp_b2,
    const float* __restrict__ head_W,  const float* __restrict__ head_b,
    float* __restrict__ out)
{
    __shared__ __align__(16) float xrl[344];            // xrl[i]=x_raw[i-3], pad i<3
    __shared__ __align__(16) float xprojT[20*XCP];      // 10.6 KB
    __shared__ __align__(16) float xcbuf[2][NG][CHK*XCP]; // 50.7 KB double-buffered
    __shared__ __align__(16) float Bsh[NG][CHK][DSTATE];
    __shared__ __align__(16) float dtraw[NG][CHK][4];
    __shared__ float xcl[DINNER], zsil[DINNER], Cl[DSTATE], yv[DINNER];
    __shared__ float hfin[96], mlph[MLPH];

    const int tid = threadIdx.x;
    const int b   = blockIdx.x;
    const int g   = tid >> 7;            // group 0..3 (2 waves, wave-uniform)
    const int ch  = tid & 127;

    // ---- staging ----
    for (int i = tid; i < 339; i += 512)
        xrl[i] = (i >= 3) ? x_raw[b*LOOKBACK + i - 3] : 0.f;
    for (int idx = tid; idx < 20*DINNER; idx += 512) {
        int jj = idx >> 7, d = idx & 127;
        xprojT[jj*XCP + d] = xproj_W[d*36 + jj];
    }

    // ---- per-thread channel params (embed_* uniform -> scalar loads) ----
    float w1 = 0.f, w0 = 0.f;
    for (int dm = 0; dm < DMODEL; ++dm) {
        float w = in_W[dm*(2*DINNER) + ch];
        w1 = fmaf(embed_W[dm], w, w1);
        w0 = fmaf(embed_b[dm], w, w0);
    }
    const float4 cw = *(const float4*)&conv_W[ch*4];
    const float  cb = conv_b[ch];
    const float dtw0 = dt_W[ch],       dtw1 = dt_W[128 + ch],
                dtw2 = dt_W[256 + ch], dtw3 = dt_W[384 + ch];
    const float dtb_r = dt_b[ch];
    bool structured = true;
    #pragma unroll
    for (int i = 0; i < 16; ++i) {
        float a = __expf(A_log[ch*DSTATE + i]);
        float ex = (float)(i + 1);
        structured = structured && (fabsf(a - ex) < 1e-3f * ex);
    }
    const bool sfast = __all(structured);

    // pair-A2 task decode (waves 0-3 only): lane covers groups 2*sub, 2*sub+1
    const int a2jp  = tid / 24;              // 0..9 for tid<240
    const int a2rem = tid - a2jp*24;
    const int a2sub = a2rem / 12;            // 0 or 1
    const int a2tt  = a2rem - a2sub*12;      // 0..11
    __syncthreads();   // xrl/xprojT ready

    // ---- conv chunk 0 into buffer 0 ----
    {
        float* xw = &xcbuf[0][g][0];
        const float* xr = &xrl[g*GSEG];
        if (g == 0) {        // zero-padded taps at sequence start
            for (int tt = 0; tt < CHK; ++tt) {
                float acc = cb;
                if (tt >= 3) acc = fmaf(fmaf(xr[tt],   w1, w0), cw.x, acc);
                if (tt >= 2) acc = fmaf(fmaf(xr[tt+1], w1, w0), cw.y, acc);
                if (tt >= 1) acc = fmaf(fmaf(xr[tt+2], w1, w0), cw.z, acc);
                acc = fmaf(fmaf(xr[tt+3], w1, w0), cw.w, acc);
                xw[tt*XCP + ch] = silu_f(acc);
            }
        } else {
            float e0 = fmaf(xr[0], w1, w0);
            float e1 = fmaf(xr[1], w1, w0);
            float e2 = fmaf(xr[2], w1, w0);
            #pragma unroll
            for (int tt = 0; tt < CHK; ++tt) {
                float e3 = fmaf(xr[tt+3], w1, w0);
                float acc = cb + e0*cw.x + e1*cw.y + e2*cw.z + e3*cw.w;
                xw[tt*XCP + ch] = silu_f(acc);
                e0 = e1; e1 = e2; e2 = e3;
            }
        }
    }
    __syncthreads();

    // ---- main loop: A2(c) | bar | scan(c) || conv(c+1) | bar ----
    v2f h01={0,0},h23={0,0},h45={0,0},h67={0,0},
        h89={0,0},hAB={0,0},hCD={0,0},hEF={0,0};
    float dacc = 0.f;

    for (int c = 0; c < NCH; ++c) {
        const int buf = c & 1;

        // pair-A2: [12 x 128] @ [128 x 20] for all 4 groups on waves 0-3;
        // each lane: 1 xproj column pair (broadcast within 24-lane span),
        // 2 xrows (one per group of its pair). 512 b128/block/chunk vs 768.
        if (tid < 240) {
            const int ga = a2sub*2, gb = a2sub*2 + 1;
            const int j0 = a2jp*2;
            const float* p0  = &xprojT[j0*XCP];
            const float* p1  = &xprojT[(j0+1)*XCP];
            const float* xra = &xcbuf[buf][ga][a2tt*XCP];
            const float* xrb = &xcbuf[buf][gb][a2tt*XCP];
            v2f a0a={0,0}, a1a={0,0}, a0b={0,0}, a1b={0,0};
            #pragma unroll 4
            for (int d = 0; d < DINNER; d += 4) {
                float4 q0 = *(const float4*)(p0 + d);
                float4 q1 = *(const float4*)(p1 + d);
                float4 xa = *(const float4*)(xra + d);
                float4 xb = *(const float4*)(xrb + d);
                v2f q0l={q0.x,q0.y}, q0h={q0.z,q0.w};
                v2f q1l={q1.x,q1.y}, q1h={q1.z,q1.w};
                v2f xal={xa.x,xa.y}, xah={xa.z,xa.w};
                v2f xbl={xb.x,xb.y}, xbh={xb.z,xb.w};
                a0a = __builtin_elementwise_fma(xal, q0l, a0a);
                a0a = __builtin_elementwise_fma(xah, q0h, a0a);
                a1a = __builtin_elementwise_fma(xal, q1l, a1a);
                a1a = __builtin_elementwise_fma(xah, q1h, a1a);
                a0b = __builtin_elementwise_fma(xbl, q0l, a0b);
                a0b = __builtin_elementwise_fma(xbh, q0h, a0b);
                a1b = __builtin_elementwise_fma(xbl, q1l, a1b);
                a1b = __builtin_elementwise_fma(xbh, q1h, a1b);
            }
            float r0a=a0a.x+a0a.y, r1a=a1a.x+a1a.y;
            float r0b=a0b.x+a0b.y, r1b=a1b.x+a1b.y;
            if (j0 < 4) {
                *(float2*)&dtraw[ga][a2tt][j0] = make_float2(r0a, r1a);
                *(float2*)&dtraw[gb][a2tt][j0] = make_float2(r0b, r1b);
            } else {
                *(float2*)&Bsh[ga][a2tt][j0-4] = make_float2(r0a, r1a);
                *(float2*)&Bsh[gb][a2tt][j0-4] = make_float2(r0b, r1b);
            }
        }
        __syncthreads();

        // scan chunk c (reads buf) — conv chunk c+1 (writes buf^1) follows in
        // the SAME phase: independent stream fills the scan's trans latency.
        const float* xs = &xcbuf[buf][g][0];
        if (__builtin_expect(sfast, 1)) {
            #pragma unroll
            for (int tt = 0; tt < CHK; ++tt) {
                float4 dr = *(const float4*)&dtraw[g][tt][0];    // broadcast
                float dv = fmaf(dr.x, dtw0, fmaf(dr.y, dtw1,
                           fmaf(dr.z, dtw2, fmaf(dr.w, dtw3, dtb_r))));
                float e  = __expf(dv);
                float p  = 1.f + e;
                float r  = fast_rcp(p);                  // exp(-delta)
                float dl = (dv > 80.f) ? dv : __logf(p); // delta
                dacc += dl;
                float ux = dl * xs[tt*XCP + ch];
                float4 B0 = *(const float4*)&Bsh[g][tt][0];
                float4 B1 = *(const float4*)&Bsh[g][tt][4];
                float4 B2 = *(const float4*)&Bsh[g][tt][8];
                float4 B3 = *(const float4*)&Bsh[g][tt][12];
                float r2 = r*r;
                v2f r2v = {r2, r2};
                v2f p01 = {r, r2};
                v2f p23 = p01*r2v, p45 = p23*r2v, p67 = p45*r2v, p89 = p67*r2v,
                    pAB = p89*r2v, pCD = pAB*r2v, pEF = pCD*r2v;
                v2f uxv = {ux, ux};
                h01 = __builtin_elementwise_fma(p01, h01, uxv*(v2f){B0.x,B0.y});
                h23 = __builtin_elementwise_fma(p23, h23, uxv*(v2f){B0.z,B0.w});
                h45 = __builtin_elementwise_fma(p45, h45, uxv*(v2f){B1.x,B1.y});
                h67 = __builtin_elementwise_fma(p67, h67, uxv*(v2f){B1.z,B1.w});
                h89 = __builtin_elementwise_fma(p89, h89, uxv*(v2f){B2.x,B2.y});
                hAB = __builtin_elementwise_fma(pAB, hAB, uxv*(v2f){B2.z,B2.w});
                hCD = __builtin_elementwise_fma(pCD, hCD, uxv*(v2f){B3.x,B3.y});
                hEF = __builtin_elementwise_fma(pEF, hEF, uxv*(v2f){B3.z,B3.w});
            }
        } else {
            const float* Arow = A_log + ch*DSTATE;
            for (int tt = 0; tt < CHK; ++tt) {
                float4 dr = *(const float4*)&dtraw[g][tt][0];
                float dv = fmaf(dr.x, dtw0, fmaf(dr.y, dtw1,
                           fmaf(dr.z, dtw2, fmaf(dr.w, dtw3, dtb_r))));
                float e  = __expf(dv);
                float dl = (dv > 15.f) ? dv : __logf(1.f + e);
                dacc += dl;
                float ux = dl * xs[tt*XCP + ch];
                const float* Brow = &Bsh[g][tt][0];
                float hv[16] = {h01.x,h01.y,h23.x,h23.y,h45.x,h45.y,h67.x,h67.y,
                                h89.x,h89.y,hAB.x,hAB.y,hCD.x,hCD.y,hEF.x,hEF.y};
                for (int i = 0; i < 16; ++i)
                    hv[i] = fmaf(__expf(-__expf(Arow[i])*dl), hv[i], ux*Brow[i]);
                h01=(v2f){hv[0],hv[1]};   h23=(v2f){hv[2],hv[3]};
                h45=(v2f){hv[4],hv[5]};   h67=(v2f){hv[6],hv[7]};
                h89=(v2f){hv[8],hv[9]};   hAB=(v2f){hv[10],hv[11]};
                hCD=(v2f){hv[12],hv[13]}; hEF=(v2f){hv[14],hv[15]};
            }
        }

        if (c + 1 < NCH) {   // conv chunk c+1 into the other buffer (t0 >= 12)
            float* xw = &xcbuf[buf^1][g][0];
            const float* xr = &xrl[g*GSEG + (c+1)*CHK];
            float e0 = fmaf(xr[0], w1, w0);
            float e1 = fmaf(xr[1], w1, w0);
            float e2 = fmaf(xr[2], w1, w0);
            float v = 0.f;
            #pragma unroll
            for (int tt = 0; tt < CHK; ++tt) {
                float e3 = fmaf(xr[tt+3], w1, w0);
                float acc = cb + e0*cw.x + e1*cw.y + e2*cw.z + e3*cw.w;
                v = silu_f(acc);
                xw[tt*XCP + ch] = v;
                e0 = e1; e1 = e2; e2 = e3;
            }
            if (g == NG-1 && c + 1 == NCH-1) xcl[ch] = v;    // t = 335
        }
        __syncthreads();   // scan reads + conv writes done before next A2
    }

    // ---- write partials to LDS (overlay dead xcbuf / Bsh regions) ----
    float* hpart = &xcbuf[0][0][0];      // needs 512*HSTR = 10240 <= 12672
    float* dsum  = &Bsh[0][0][0];        // needs 512 <= 768
    {
        float4* hp = (float4*)&hpart[(g*128 + ch)*HSTR];
        hp[0] = make_float4(h01.x,h01.y,h23.x,h23.y);
        hp[1] = make_float4(h45.x,h45.y,h67.x,h67.y);
        hp[2] = make_float4(h89.x,h89.y,hAB.x,hAB.y);
        hp[3] = make_float4(hCD.x,hCD.y,hEF.x,hEF.y);
        dsum[g*128 + ch] = dacc;
    }
    __syncthreads();

    // ---- E1 (parallel): combine | z-gate | C | mlp1 ----
    float H[16];
    if (tid < 128) {
        {
            const float4* hp = (const float4*)&hpart[tid*HSTR];
            float4 a = hp[0], bq = hp[1], cq = hp[2], dq = hp[3];
            H[0]=a.x;  H[1]=a.y;  H[2]=a.z;  H[3]=a.w;
            H[4]=bq.x; H[5]=bq.y; H[6]=bq.z; H[7]=bq.w;
            H[8]=cq.x; H[9]=cq.y; H[10]=cq.z;H[11]=cq.w;
            H[12]=dq.x;H[13]=dq.y;H[14]=dq.z;H[15]=dq.w;
        }
        for (int gg = 1; gg < NG; ++gg) {
            float D = dsum[gg*128 + tid];
            const float4* hp = (const float4*)&hpart[(gg*128 + tid)*HSTR];
            float4 a = hp[0], bq = hp[1], cq = hp[2], dq = hp[3];
            float hg[16] = {a.x,a.y,a.z,a.w,bq.x,bq.y,bq.z,bq.w,
                            cq.x,cq.y,cq.z,cq.w,dq.x,dq.y,dq.z,dq.w};
            if (structured) {
                float r = __expf(-D);
                float pw = 1.f;
                #pragma unroll
                for (int i = 0; i < 16; ++i) {
                    pw *= r;                      // r^(i+1)
                    H[i] = fmaf(pw, H[i], hg[i]);
                }
            } else {
                #pragma unroll
                for (int i = 0; i < 16; ++i)
                    H[i] = fmaf(__expf(-__expf(A_log[tid*DSTATE+i])*D), H[i], hg[i]);
            }
        }
    } else if (tid < 256) {
        const int c2 = tid - 128;                 // z-gate channel
        float a1 = 0.f, a0 = 0.f;
        for (int dm = 0; dm < DMODEL; ++dm) {
            float w = in_W[dm*(2*DINNER) + DINNER + c2];
            a1 = fmaf(embed_W[dm], w, a1);
            a0 = fmaf(embed_b[dm], w, a0);
        }
        float zv = fmaf(xrl[338], a1, a0);        // x_raw[335]
        zsil[c2] = silu_f(zv);
    } else if (tid < 320) {
        const int lane = tid - 256;               // C at t=335 (one wave)
        const int n = lane & 15, q = lane >> 4;
        float acc = 0.f;
        for (int d = q*32; d < q*32 + 32; ++d)
            acc = fmaf(xcl[d], xproj_W[d*36 + 20 + n], acc);
        acc += __shfl_xor(acc, 16);
        acc += __shfl_xor(acc, 32);
        if (lane < 16) Cl[n] = acc;
    } else if (tid >= 384) {
        const int lane = tid - 384;               // mlp1 (2 waves)
        const int j = lane >> 1, k = lane & 1;
        const float* xf = x_features + b*NFEAT;
        float acc = 0.f;
        const int f0 = k*82, f1 = (k ? NFEAT : 82);
        for (int f = f0; f < f1; ++f)
            acc = fmaf(xf[f], mlp_W1[f*MLPH + j], acc);
        acc += __shfl_xor(acc, 1);
        if (k == 0) mlph[j] = fmaxf(acc + mlp_b1[j], 0.f);
    }
    __syncthreads();

    // ---- E2: y (tid<128) | mlp2 (tid 128..191) ----
    if (tid < 128) {
        float acc = 0.f;
        #pragma unroll
        for (int i = 0; i < 16; ++i) acc = fmaf(H[i], Cl[i], acc);
        float y = acc + xcl[tid]*Dvec[tid];
        yv[tid] = y * zsil[tid];
    } else if (tid < 192) {
        const int lane = tid - 128;
        const int j = lane >> 1, k = lane & 1;
        float acc = 0.f;
        for (int kk = k*32; kk < k*32 + 32; ++kk)
            acc = fmaf(mlph[kk], mlp_W2[kk*32 + j], acc);
        acc += __shfl_xor(acc, 1);
        if (k == 0) hfin[64 + j] = acc + mlp_b2[j];
    }
    __syncthreads();

    // ---- E3: out projection (tid<256) ----
    if (tid < 256) {
        const int o = tid >> 2, k = tid & 3;
        float acc = 0.f;
        for (int d = k*32; d < k*32 + 32; ++d)
            acc = fmaf(yv[d], out_W[d*DMODEL + o], acc);
        acc += __shfl_xor(acc, 1);
        acc += __shfl_xor(acc, 2);
        if (k == 0) hfin[o] = acc;
    }
    __syncthreads();

    // ---- E4: head ----
    if (tid < 192) {
        const int o = tid >> 1, k = tid & 1;
        float acc = 0.f;
        for (int i = k*48; i < k*48 + 48; ++i)
            acc = fmaf(hfin[i], head_W[i*HORIZON + o], acc);
        acc += __shfl_xor(acc, 1);
        if (k == 0) out[b*HORIZON + o] = acc + head_b[o];
    }
}

extern "C" void kernel_launch(void* const* d_in, const int* in_sizes, int n_in,
                              void* d_out, int out_size, void* d_ws, size_t ws_size,
                              hipStream_t stream) {
    (void)in_sizes; (void)n_in; (void)out_size; (void)d_ws; (void)ws_size;
    mamba_one<<<BATCH, 512, 0, stream>>>(
        (const float*)d_in[0],  (const float*)d_in[1],  (const float*)d_in[2],
        (const float*)d_in[3],  (const float*)d_in[4],  (const float*)d_in[5],
        (const float*)d_in[6],  (const float*)d_in[7],  (const float*)d_in[8],
        (const float*)d_in[9],  (const float*)d_in[10], (const float*)d_in[11],
        (const float*)d_in[12], (const float*)d_in[13], (const float*)d_in[14],
        (const float*)d_in[15], (const float*)d_in[16], (const float*)d_in[17],
        (const float*)d_in[18], (float*)d_out);
}